// Round 14
// baseline (435.024 us; speedup 1.0000x reference)
//
#include <hip/hip_runtime.h>
#include <hip/hip_bf16.h>
#include <math.h>

// AttentionCritic fused pipeline, round 14:
//  R13 config (best: 433us) with ONE change — attn de-synchronized:
//   * tiles are wave-private, so both __syncthreads removed (R10/R11 proved the pattern);
//   * softmax weights via __shfl broadcast (wL LDS roundtrip removed);
//   * kvs loads widened to uint4 (6x16B per lane, issued up-front), unpack-once to f32 tiles
//     (keeps R9's cheap f32 inner loops — R10's per-FMA bf16 unpack was the regression).
// A=8, B=8192, S=128, ADIM=16, H=512, HEADS=4, D=128. Output f32.

#define AN 8
#define BNB 8192
#define SN 128
#define ADN 16
#define HN 512
#define NHEADS 4
#define DN 128

typedef __hip_bfloat16 bf16;
typedef unsigned short u16;
typedef __attribute__((ext_vector_type(8))) short bf16x8;
typedef __attribute__((ext_vector_type(4))) float f32x4;

__device__ __forceinline__ float lrelu(float x){ return x > 0.f ? x : 0.01f*x; }
__device__ __forceinline__ float bflo(unsigned u){ return __uint_as_float(u << 16); }
__device__ __forceinline__ float bfhi(unsigned u){ return __uint_as_float(u & 0xffff0000u); }
__device__ __forceinline__ float bf2f(u16 u){ return __uint_as_float((unsigned)u << 16); }
__device__ __forceinline__ u16 f2bf(float v){
  union { bf16 h; u16 s; } cv; cv.h = __float2bfloat16(v); return cv.s;
}
__device__ __forceinline__ ushort4 f4bf(float4 v){
  ushort4 u; u.x=f2bf(v.x); u.y=f2bf(v.y); u.z=f2bf(v.z); u.w=f2bf(v.w); return u;
}

// async global->LDS, 16B per lane; LDS dest is wave-uniform base + lane*16
__device__ __forceinline__ void gload16(const u16* g, u16* l){
  __builtin_amdgcn_global_load_lds(
      (const __attribute__((address_space(1))) unsigned int*)(g),
      (__attribute__((address_space(3))) unsigned int*)(l), 16, 0, 0);
}

// ---------------- prep: bf16-pack sa rows [65536][192] + LN stats + action argmax ------------
__global__ __launch_bounds__(256) void prep_kernel(
    const float* __restrict__ states, const float* __restrict__ actions,
    u16* __restrict__ sa_bf, float2* __restrict__ st_s, float2* __restrict__ st_sa,
    int* __restrict__ aip)
{
  const int lane = threadIdx.x & 63;
  const int r = blockIdx.x*4 + (threadIdx.x >> 6);
  float2 sv = ((const float2*)(states + (size_t)r*SN))[lane];
  float s1 = sv.x + sv.y, q1 = sv.x*sv.x + sv.y*sv.y;
  float2 av = make_float2(0.f, 0.f);
  if (lane < 8) av = ((const float2*)(actions + (size_t)r*ADN))[lane];
  float s2 = s1 + av.x + av.y, q2 = q1 + av.x*av.x + av.y*av.y;
  #pragma unroll
  for (int off=32; off; off>>=1){
    s1 += __shfl_xor(s1,off); q1 += __shfl_xor(q1,off);
    s2 += __shfl_xor(s2,off); q2 += __shfl_xor(q2,off);
  }
  float bv; int bi;
  if (lane < 8){
    if (av.x >= av.y){ bv = av.x; bi = 2*lane; } else { bv = av.y; bi = 2*lane+1; }
  } else { bv = -INFINITY; bi = 999; }
  #pragma unroll
  for (int off=1; off<8; off<<=1){
    float ov = __shfl_xor(bv, off); int oi = __shfl_xor(bi, off);
    if (ov > bv || (ov == bv && oi < bi)){ bv = ov; bi = oi; }
  }
  u16* row = sa_bf + (size_t)r*192;
  ushort2 p; p.x = f2bf(sv.x); p.y = f2bf(sv.y);
  *(ushort2*)(row + 2*lane) = p;
  if (lane < 8){
    ushort2 pa; pa.x = f2bf(av.x); pa.y = f2bf(av.y);
    *(ushort2*)(row + 128 + 2*lane) = pa;
  } else if (lane < 32){
    ushort2 z; z.x = 0; z.y = 0;
    *(ushort2*)(row + 128 + 2*lane) = z;
  }
  if (lane==0){
    float m1 = s1*(1.f/128.f), v1 = fmaxf(q1*(1.f/128.f)-m1*m1, 0.f);
    st_s[r] = make_float2(m1, rsqrtf(v1+1e-5f));
    float m2 = s2*(1.f/144.f), v2 = fmaxf(q2*(1.f/144.f)-m2*m2, 0.f);
    st_sa[r] = make_float2(m2, rsqrtf(v2+1e-5f));
    aip[r] = bi;
  }
}

// ---------------- all weight transposes in one launch: [Z][K][N] f32 -> [Z][N][Kp] bf16 ------
__global__ __launch_bounds__(256) void transw_all_kernel(
    const float* __restrict__ Ws_s, const float* __restrict__ Ws_sa, const float* __restrict__ Wc1,
    const float* __restrict__ Wk, const float* __restrict__ Wv, const float* __restrict__ Wsel,
    u16* __restrict__ Wt_s, u16* __restrict__ Wt_sa, u16* __restrict__ Wt_c1, u16* __restrict__ Wt_p)
{
  __shared__ float t[32][33];
  int id = blockIdx.x;
  const float* in; u16* outp; int K, Kp; size_t zs; int gx;
  const int N = (id < 5376) ? 512 : 128;
  if (id < 512){            in=Ws_s;  outp=Wt_s;            K=128;  Kp=128;  zs=(size_t)512*128;  gx=4;  }
  else if (id < 1280){ id-=512;  in=Ws_sa; outp=Wt_sa;      K=144;  Kp=192;  zs=(size_t)512*192;  gx=6;  }
  else if (id < 5376){ id-=1280; in=Wc1;   outp=Wt_c1;      K=1024; Kp=1024; zs=(size_t)512*1024; gx=32; }
  else if (id < 5632){ id-=5376; in=Wk;    outp=Wt_p;            K=512; Kp=512; zs=(size_t)3*128*512; gx=16; }
  else if (id < 5888){ id-=5632; in=Wv;    outp=Wt_p+128*512;    K=512; Kp=512; zs=(size_t)3*128*512; gx=16; }
  else {               id-=5888; in=Wsel;  outp=Wt_p+2*128*512;  K=512; Kp=512; zs=(size_t)3*128*512; gx=16; }
  const int bx = id % gx; id /= gx;
  const int gy = N >> 5;
  const int by = id % gy;
  const int z  = id / gy;
  const int tx = threadIdx.x, ty = threadIdx.y;
  const int k0 = bx*32, n0 = by*32;
  const float* ip = in + (size_t)z*K*N;
  #pragma unroll
  for (int i=0;i<4;i++){
    int k = k0 + ty*4 + i;
    t[ty*4+i][tx] = (k < K) ? ip[(size_t)k*N + n0 + tx] : 0.f;
  }
  __syncthreads();
  u16* op = outp + (size_t)z*zs;
  #pragma unroll
  for (int i=0;i<4;i++){
    int n = n0 + ty*4 + i;
    op[(size_t)n*Kp + k0 + tx] = f2bf(t[tx][ty*4+i]);
  }
}

// ---------------- column sums from transposed bf16 weights (row-sums, 1 wave/row) ------------
__global__ __launch_bounds__(256) void colsum_bf_kernel(
    const u16* __restrict__ Wt_s, const u16* __restrict__ Wt_sa, const u16* __restrict__ Wt_c1,
    float* __restrict__ cs_s, float* __restrict__ cs_sa, float* __restrict__ cs_c1)
{
  const int lane = threadIdx.x & 63;
  const int row = blockIdx.x*4 + (threadIdx.x >> 6);
  const int which = row >> 12; const int idx = row & 4095;
  const u16* W; int K; float* outp;
  if (which==0){ W = Wt_s;  K = 128;  outp = cs_s;  }
  else if (which==1){ W = Wt_sa; K = 192;  outp = cs_sa; }
  else { W = Wt_c1; K = 1024; outp = cs_c1; }
  const u16* p = W + (size_t)idx*K;
  float s = 0.f;
  for (int c = lane*8; c < K; c += 512){
    uint4 v = *(const uint4*)(p + c);
    const unsigned w4[4] = {v.x, v.y, v.z, v.w};
    #pragma unroll
    for (int t=0;t<4;t++) s += bflo(w4[t]) + bfhi(w4[t]);
  }
  #pragma unroll
  for (int off=32; off; off>>=1) s += __shfl_xor(s,off);
  if (lane==0) outp[idx] = s;
}

// ---------------- MFMA GEMM + LN-fold epilogue (128x128 tile, encoders); 32KB LDS ------------
// MODE 0: s_enc = lrelu(ln(states)@Ws_s + bs_s)   K=128  A=sa_bf(lda 192)
// MODE 1: sa_enc= lrelu(ln([s|a])@Ws_sa + bs_sa)  K=192
template<int MODE>
__global__ __launch_bounds__(256, 4) void mfma_enc_kernel(
    const u16* __restrict__ Aa,
    const u16* __restrict__ Wt, const float* __restrict__ bias,
    const float2* __restrict__ stats, const float* __restrict__ csum,
    u16* __restrict__ outp)
{
  constexpr int K   = (MODE==0) ? 128 : 192;
  constexpr int LDA = 192;
  constexpr int KP  = K;
  __shared__ __align__(16) u16 smem[16384];   // As 16KB | Bs 16KB; epilogue reuses as [64][136]
  u16* As = smem;
  u16* Bs = smem + 8192;
  const int tid = threadIdx.x;
  const int w = tid>>6, lane = tid&63;
  const int wr = w>>1, wc = w&1;
  const int srow = lane>>3, skq = (lane&7)^srow;
  const int slotx = lane>>4, lr = lane&15;

  const int nwg = gridDim.x * gridDim.y;
  int id = blockIdx.y * gridDim.x + blockIdx.x;
  int swz = (id & 7) * (nwg >> 3) + (id >> 3);
  const int bx = swz % gridDim.x, by = swz / gridDim.x;

  const int m0 = by*128, n0c = bx*128;
  const int a = by >> 6;
  const u16* Wbase = Wt + (size_t)a*HN*KP;
  const int slotbase = slotx ^ (lane&7);
  f32x4 acc[4][4] = {};

  for (int k0 = 0; k0 < K; k0 += 64){
    __syncthreads();
    #pragma unroll
    for (int t=0;t<4;t++){
      const int rr = w*32 + t*8;
      gload16(Aa    + (size_t)(m0  + rr + srow)*LDA + k0 + skq*8, As + rr*64);
      gload16(Wbase + (size_t)(n0c + rr + srow)*KP  + k0 + skq*8, Bs + rr*64);
    }
    __syncthreads();
    #pragma unroll
    for (int ks=0; ks<2; ++ks){
      bf16x8 af[4], bv[4];
      const int so = ((slotbase ^ (ks<<2)))*8;
      #pragma unroll
      for (int mi=0;mi<4;mi++) af[mi] = *(const bf16x8*)&As[(wr*64+mi*16+lr)*64 + so];
      #pragma unroll
      for (int ni=0;ni<4;ni++) bv[ni] = *(const bf16x8*)&Bs[(wc*64+ni*16+lr)*64 + so];
      #pragma unroll
      for (int mi=0;mi<4;mi++)
        #pragma unroll
        for (int ni=0;ni<4;ni++)
          acc[mi][ni] = __builtin_amdgcn_mfma_f32_16x16x32_bf16(af[mi], bv[ni], acc[mi][ni], 0, 0, 0);
    }
  }

  __syncthreads();
  float csv[4], biv[4];
  #pragma unroll
  for (int ni=0;ni<4;ni++){
    const int col = n0c + wc*64 + ni*16 + lr;
    csv[ni] = csum[a*HN + col];
    biv[ni] = bias[a*HN + col];
  }
  // two-pass epilogue: pass p stages rows p*64..p*64+63 into smem[64][136]
  #pragma unroll
  for (int pass=0; pass<2; ++pass){
    if (wr == pass){
      #pragma unroll
      for (int mi=0;mi<4;mi++){
        const int rloc = mi*16 + slotx*4;
        #pragma unroll
        for (int v=0; v<4; ++v){
          const float2 st = stats[m0 + pass*64 + rloc + v];
          #pragma unroll
          for (int ni=0;ni<4;ni++){
            const float o = lrelu(st.y*(acc[mi][ni][v] - st.x*csv[ni]) + biv[ni]);
            smem[(rloc+v)*136 + wc*64 + ni*16 + lr] = f2bf(o);
          }
        }
      }
    }
    __syncthreads();
    #pragma unroll
    for (int it=0; it<4; ++it){
      const int rl = it*16 + (tid>>4);
      const int ck = (tid&15)*8;
      const uint4 vv = *(const uint4*)&smem[rl*136 + ck];
      *(uint4*)(outp + (size_t)(m0 + pass*64 + rl)*HN + n0c + ck) = vv;
    }
    __syncthreads();
  }
}

// ---------------- critic: 128x128 + fused final; 32KB LDS (wc2l loaded in epilogue) ----------
// q += (lrelu(ln([s_enc|values])@Wc1 + bc1)) . Wc2[:,argmax];  K=1024, atomicAdd f32.
__global__ __launch_bounds__(256, 4) void mfma_critic_kernel(
    const u16* __restrict__ Aa, const u16* __restrict__ Ab,
    const u16* __restrict__ Wt, const float* __restrict__ bias,
    const float2* __restrict__ stats, const float* __restrict__ csum,
    const float* __restrict__ Wc2, const float* __restrict__ bc2,
    const int* __restrict__ aip, float* __restrict__ qout)
{
  __shared__ __align__(16) u16 smem[16384];   // As|Bs during loop; wc2l[16][128]+ail after
  u16* As = smem;
  u16* Bs = smem + 8192;
  const int tid = threadIdx.x;
  const int w = tid>>6, lane = tid&63;
  const int wr = w>>1, wc = w&1;
  const int srow = lane>>3, skq = (lane&7)^srow;
  const int slotx = lane>>4, lr = lane&15;

  const int nwg = gridDim.x * gridDim.y;     // (4,512) = 2048, %8==0
  int id = blockIdx.y * gridDim.x + blockIdx.x;
  int swz = (id & 7) * (nwg >> 3) + (id >> 3);
  const int bx = swz % gridDim.x, by = swz / gridDim.x;

  const int m0 = by*128, n0c = bx*128;
  const int a = by >> 6;
  const u16* Wbase = Wt + (size_t)a*HN*1024;
  const int slotbase = slotx ^ (lane&7);
  f32x4 acc[4][4] = {};

  for (int k0 = 0; k0 < 1024; k0 += 64){
    __syncthreads();
    const u16* asrc = (k0 < 512) ? Aa : Ab;
    const int acol = k0 & 511;
    #pragma unroll
    for (int t=0;t<4;t++){
      const int rr = w*32 + t*8;
      gload16(asrc  + (size_t)(m0  + rr + srow)*HN   + acol + skq*8, As + rr*64);
      gload16(Wbase + (size_t)(n0c + rr + srow)*1024 + k0   + skq*8, Bs + rr*64);
    }
    __syncthreads();
    #pragma unroll
    for (int ks=0; ks<2; ++ks){
      bf16x8 af[4], bv[4];
      const int so = ((slotbase ^ (ks<<2)))*8;
      #pragma unroll
      for (int mi=0;mi<4;mi++) af[mi] = *(const bf16x8*)&As[(wr*64+mi*16+lr)*64 + so];
      #pragma unroll
      for (int ni=0;ni<4;ni++) bv[ni] = *(const bf16x8*)&Bs[(wc*64+ni*16+lr)*64 + so];
      #pragma unroll
      for (int mi=0;mi<4;mi++)
        #pragma unroll
        for (int ni=0;ni<4;ni++)
          acc[mi][ni] = __builtin_amdgcn_mfma_f32_16x16x32_bf16(af[mi], bv[ni], acc[mi][ni], 0, 0, 0);
    }
  }

  __syncthreads();
  // load Wc2 slice into freed As region: wc2l[aidx][col] bf16 (conflict-free epilogue reads)
  u16* wc2l = smem;                   // 2048 u16
  int* ail  = (int*)(smem + 2048);    // 128 int
  const float* wsrc = Wc2 + ((size_t)a*HN + n0c)*ADN;
  #pragma unroll
  for (int i = 0; i < 8; ++i){
    const int e = i*256 + tid;        // e = col*16 + aidx
    wc2l[(e & 15)*128 + (e >> 4)] = f2bf(wsrc[e]);
  }
  if (tid < 128) ail[tid] = aip[m0 + tid];
  __syncthreads();

  float csv[4], biv[4];
  #pragma unroll
  for (int ni=0;ni<4;ni++){
    const int col = n0c + wc*64 + ni*16 + lr;
    csv[ni] = csum[a*HN + col];
    biv[ni] = bias[a*HN + col];
  }
  #pragma unroll
  for (int mi=0;mi<4;mi++){
    const int rbase = wr*64 + mi*16 + slotx*4;
    #pragma unroll
    for (int v=0; v<4; ++v){
      const int rl = rbase + v;
      const float2 st = stats[m0 + rl];
      const int aidx = ail[rl];
      float p = 0.f;
      #pragma unroll
      for (int ni=0;ni<4;ni++){
        const int coll = wc*64 + ni*16 + lr;
        const float o = lrelu(st.y*(acc[mi][ni][v] - st.x*csv[ni]) + biv[ni]);
        p = fmaf(o, bf2f(wc2l[aidx*128 + coll]), p);
      }
      p += __shfl_xor(p,1); p += __shfl_xor(p,2);
      p += __shfl_xor(p,4); p += __shfl_xor(p,8);
      if (lr == 0){
        if (n0c==0 && wc==0) p += bc2[a*ADN + aidx];
        atomicAdd(qout + m0 + rl, p);
      }
    }
  }
}

// ---------------- MFMA proj (one head): N=128 per t-block, K=512; 32KB LDS -------------------
__global__ __launch_bounds__(256, 4) void mfma_proj_kernel(
    const u16* __restrict__ sa_enc, const u16* __restrict__ Wt_p,
    const float* __restrict__ bsel, u16* __restrict__ kvs, int head)
{
  __shared__ __align__(16) u16 smem[16384];
  u16* As = smem;
  u16* Bs = smem + 8192;
  const int tid = threadIdx.x;
  const int w = tid>>6, lane = tid&63;
  const int wr = w>>1, wc = w&1;
  const int srow = lane>>3, skq = (lane&7)^srow;
  const int slotx = lane>>4, lr = lane&15;

  const int nwg = gridDim.x * gridDim.y;              // (3, 512) = 1536, %8==0
  int id = blockIdx.y * gridDim.x + blockIdx.x;
  int swz = (id & 7) * (nwg >> 3) + (id >> 3);
  const int t = swz % gridDim.x;
  const int m0 = (swz / gridDim.x) * 128;

  const u16* Wbase = Wt_p + (size_t)(head*3 + t)*DN*HN;
  const int slotbase = slotx ^ (lane&7);
  f32x4 acc[4][4] = {};

  for (int k0 = 0; k0 < HN; k0 += 64){
    __syncthreads();
    #pragma unroll
    for (int tt=0;tt<4;tt++){
      const int rr = w*32 + tt*8;
      gload16(sa_enc + (size_t)(m0 + rr + srow)*HN + k0 + skq*8, As + rr*64);
      gload16(Wbase  + (size_t)(rr + srow)*HN      + k0 + skq*8, Bs + rr*64);
    }
    __syncthreads();
    #pragma unroll
    for (int ks=0; ks<2; ++ks){
      bf16x8 af[4], bv[4];
      const int so = ((slotbase ^ (ks<<2)))*8;
      #pragma unroll
      for (int mi=0;mi<4;mi++) af[mi] = *(const bf16x8*)&As[(wr*64+mi*16+lr)*64 + so];
      #pragma unroll
      for (int ni=0;ni<4;ni++) bv[ni] = *(const bf16x8*)&Bs[(wc*64+ni*16+lr)*64 + so];
      #pragma unroll
      for (int mi=0;mi<4;mi++)
        #pragma unroll
        for (int ni=0;ni<4;ni++)
          acc[mi][ni] = __builtin_amdgcn_mfma_f32_16x16x32_bf16(af[mi], bv[ni], acc[mi][ni], 0, 0, 0);
    }
  }

  __syncthreads();
  const bool issel = (t == 2);
  float biv[4];
  #pragma unroll
  for (int ni=0;ni<4;ni++){
    const int col = wc*64 + ni*16 + lr;
    biv[ni] = issel ? bsel[head*DN + col] : 0.f;
  }
  // two-pass epilogue staging into smem[64][136]
  #pragma unroll
  for (int pass=0; pass<2; ++pass){
    if (wr == pass){
      #pragma unroll
      for (int mi=0;mi<4;mi++){
        const int rloc = mi*16 + slotx*4;
        #pragma unroll
        for (int v=0; v<4; ++v){
          #pragma unroll
          for (int ni=0;ni<4;ni++){
            float o = acc[mi][ni][v] + biv[ni];
            if (issel) o = lrelu(o);
            smem[(rloc+v)*136 + wc*64 + ni*16 + lr] = f2bf(o);
          }
        }
      }
    }
    __syncthreads();
    #pragma unroll
    for (int it=0; it<4; ++it){
      const int rl = it*16 + (tid>>4);
      const int ck = (tid&15)*8;
      const int r = m0 + pass*64 + rl;
      const int ar = r >> 13, b = r & (BNB-1);
      const uint4 vv = *(const uint4*)&smem[rl*136 + ck];
      *(uint4*)(kvs + (((size_t)t*BNB + b)*AN + ar)*DN + ck) = vv;
    }
    __syncthreads();
  }
}

// ---------------- attention: f32 wave-private tiles, NO barriers, shfl weights ---------------
__global__ __launch_bounds__(256) void attn_kernel(
    const u16* __restrict__ kvs, u16* __restrict__ values, int kh)
{
  __shared__ float lds[4][3168];   // per wave: sel[8][132], key[8][132], val[8][132]
  const int lane = threadIdx.x & 63;
  const int wv   = threadIdx.x >> 6;
  float* selL = &lds[wv][0];
  float* keyL = &lds[wv][1056];
  float* valL = &lds[wv][2112];
  const int b = blockIdx.x*4 + wv;

  // issue all 6 global loads up-front (16B each)
  uint4 vld[3][2];
  #pragma unroll
  for (int m=0;m<3;m++){
    const int t = (m==0) ? 2 : ((m==1) ? 0 : 1);   // sel, key, val
    const uint4* p = (const uint4*)(kvs + ((size_t)t*BNB + b)*(AN*DN));
    vld[m][0] = p[lane];
    vld[m][1] = p[64 + lane];
  }
  #pragma unroll
  for (int m=0;m<3;m++){
    float* dst = (m==0) ? selL : ((m==1) ? keyL : valL);
    #pragma unroll
    for (int it=0; it<2; it++){
      const uint4 u = vld[m][it];
      const int e = (it*64 + lane)*8;
      const int j = e >> 7, d = e & 127;
      float4 f0, f1;
      f0.x = bflo(u.x); f0.y = bfhi(u.x); f0.z = bflo(u.y); f0.w = bfhi(u.y);
      f1.x = bflo(u.z); f1.y = bfhi(u.z); f1.z = bflo(u.w); f1.w = bfhi(u.w);
      *(float4*)&dst[j*132 + d]     = f0;
      *(float4*)&dst[j*132 + d + 4] = f1;
    }
  }
  // tiles are wave-private: in-wave LDS ordering suffices (no __syncthreads)

  const int i = lane >> 3, j = lane & 7;
  float acc = 0.f;
  #pragma unroll 8
  for (int dq=0; dq<32; dq++){
    const float4 s4 = *(const float4*)&selL[i*132 + dq*4];
    const float4 k4 = *(const float4*)&keyL[j*132 + dq*4];
    acc += s4.x*k4.x + s4.y*k4.y + s4.z*k4.z + s4.w*k4.w;
  }
  float logit = acc * 0.08838834764831845f;   // 1/sqrt(128)
  if (i == j) logit = -INFINITY;
  float mx = logit;
  mx = fmaxf(mx, __shfl_xor(mx,1,8));
  mx = fmaxf(mx, __shfl_xor(mx,2,8));
  mx = fmaxf(mx, __shfl_xor(mx,4,8));
  const float e = __expf(logit - mx);
  float ssum = e;
  ssum += __shfl_xor(ssum,1,8);
  ssum += __shfl_xor(ssum,2,8);
  ssum += __shfl_xor(ssum,4,8);
  const float wgt = e / ssum;

  const int dq = lane & 7;
  float4 o[4];
  #pragma unroll
  for (int tt=0;tt<4;tt++) o[tt] = make_float4(0.f,0.f,0.f,0.f);
  #pragma unroll
  for (int jj=0;jj<8;jj++){
    const float wj = __shfl(wgt, i*8 + jj);
    #pragma unroll
    for (int tt=0;tt<4;tt++){
      const float4 v4 = *(const float4*)&valL[jj*132 + tt*32 + dq*4];
      o[tt].x += wj*v4.x; o[tt].y += wj*v4.y; o[tt].z += wj*v4.z; o[tt].w += wj*v4.w;
    }
  }
  u16* dst = values + ((size_t)i*BNB + b)*HN + kh*DN;
  #pragma unroll
  for (int tt=0;tt<4;tt++)
    *(ushort4*)(dst + tt*32 + dq*4) = f4bf(o[tt]);
}

// ---------------- per-row stats of cin = concat(s_enc, values) (1024), bf16 inputs -----------
__global__ __launch_bounds__(256) void stats_cin_kernel(
    const u16* __restrict__ s_enc, const u16* __restrict__ values, float2* __restrict__ st)
{
  const int lane = threadIdx.x & 63;
  const int r = blockIdx.x*4 + (threadIdx.x >> 6);
  const uint4* p1 = (const uint4*)(s_enc + (size_t)r*HN);
  const uint4* p2 = (const uint4*)(values + (size_t)r*HN);
  uint4 va = p1[lane];
  uint4 vb = p2[lane];
  float s=0.f, q=0.f;
  const unsigned wa[4] = {va.x, va.y, va.z, va.w};
  const unsigned wb[4] = {vb.x, vb.y, vb.z, vb.w};
  #pragma unroll
  for (int t=0;t<4;t++){
    float f0 = bflo(wa[t]), f1 = bfhi(wa[t]);
    float g0 = bflo(wb[t]), g1 = bfhi(wb[t]);
    s += f0+f1+g0+g1; q += f0*f0+f1*f1+g0*g0+g1*g1;
  }
  #pragma unroll
  for (int off=32; off; off>>=1){ s += __shfl_xor(s,off); q += __shfl_xor(q,off); }
  if (lane==0){
    float m = s*(1.f/1024.f); float v = fmaxf(q*(1.f/1024.f) - m*m, 0.f);
    st[r] = make_float2(m, rsqrtf(v + 1e-5f));
  }
}

extern "C" void kernel_launch(void* const* d_in, const int* in_sizes, int n_in,
                              void* d_out, int out_size, void* d_ws, size_t ws_size,
                              hipStream_t stream)
{
  (void)in_sizes; (void)n_in; (void)ws_size;
  const float* states  = (const float*)d_in[0];
  const float* actions = (const float*)d_in[1];
  const float* Ws_s    = (const float*)d_in[2];
  const float* bs_s    = (const float*)d_in[3];
  const float* Ws_sa   = (const float*)d_in[4];
  const float* bs_sa   = (const float*)d_in[5];
  const float* Wk      = (const float*)d_in[6];
  const float* Wv      = (const float*)d_in[7];
  const float* Wsel    = (const float*)d_in[8];
  const float* bsel    = (const float*)d_in[9];
  const float* Wc1     = (const float*)d_in[10];
  const float* bc1     = (const float*)d_in[11];
  const float* Wc2     = (const float*)d_in[12];
  const float* bc2     = (const float*)d_in[13];
  float* outp = (float*)d_out;

  char* ws = (char*)d_ws;
  size_t off = 0;
  auto alloc = [&](size_t n){ void* p = ws + off; off += (n + 255) & ~(size_t)255; return p; };
  u16*    slot1  = (u16*)   alloc((size_t)AN*BNB*HN*2);   // 64 MB: kvs during attn loop, s_enc after
  u16*    s_enc  = slot1;
  u16*    kvs    = slot1;                                  // 48 MB <= 64 MB
  u16*    sa_enc = (u16*)   alloc((size_t)AN*BNB*HN*2);   // 64 MB
  u16*    values = (u16*)   alloc((size_t)AN*BNB*HN*2);   // 64 MB
  u16*    sa_bf  = (u16*)   alloc((size_t)AN*BNB*192*2);  // 24 MB
  u16*    Wt_s   = (u16*)   alloc((size_t)AN*HN*128*2);
  u16*    Wt_sa  = (u16*)   alloc((size_t)AN*HN*192*2);
  u16*    Wt_c1  = (u16*)   alloc((size_t)AN*HN*1024*2);
  u16*    Wt_p   = (u16*)   alloc((size_t)NHEADS*3*DN*HN*2);
  float2* st_s   = (float2*)alloc((size_t)AN*BNB*8);
  float2* st_sa  = (float2*)alloc((size_t)AN*BNB*8);
  float2* st_cin = (float2*)alloc((size_t)AN*BNB*8);
  float*  cs_s   = (float*) alloc((size_t)AN*HN*4);
  float*  cs_sa  = (float*) alloc((size_t)AN*HN*4);
  float*  cs_c1  = (float*) alloc((size_t)AN*HN*4);
  int*    aip    = (int*)   alloc((size_t)AN*BNB*4);

  hipMemsetAsync(d_out, 0, (size_t)out_size*4, stream);
  prep_kernel<<<dim3(AN*BNB/4), 256, 0, stream>>>(states, actions, sa_bf, st_s, st_sa, aip);
  transw_all_kernel<<<dim3(6144), dim3(32,8), 0, stream>>>(
      Ws_s, Ws_sa, Wc1, Wk, Wv, Wsel, Wt_s, Wt_sa, Wt_c1, Wt_p);
  colsum_bf_kernel<<<dim3(3*AN*HN/4), 256, 0, stream>>>(Wt_s, Wt_sa, Wt_c1, cs_s, cs_sa, cs_c1);

  mfma_enc_kernel<1><<<dim3(4,512), 256, 0, stream>>>(sa_bf, Wt_sa, bs_sa, st_sa, cs_sa, sa_enc);
  for (int kh = 0; kh < NHEADS; ++kh){
    mfma_proj_kernel<<<dim3(3,512), 256, 0, stream>>>(sa_enc, Wt_p, bsel, kvs, kh);
    attn_kernel<<<dim3(BNB/4), 256, 0, stream>>>(kvs, values, kh);
  }
  mfma_enc_kernel<0><<<dim3(4,512), 256, 0, stream>>>(sa_bf, Wt_s, bs_s, st_s, cs_s, s_enc);
  stats_cin_kernel<<<dim3(AN*BNB/4), 256, 0, stream>>>(s_enc, values, st_cin);
  mfma_critic_kernel<<<dim3(4,512), 256, 0, stream>>>(s_enc, values, Wt_c1, bc1, st_cin, cs_c1,
                                                      Wc2, bc2, aip, outp);
}

// Round 16
// 430.454 us; speedup vs baseline: 1.0106x; 1.0106x over previous
//
#include <hip/hip_runtime.h>
#include <hip/hip_bf16.h>
#include <math.h>

// AttentionCritic fused pipeline, round 16: EXACT revert to R13 (best: 433.0us).
// R15's fp8 critic failed numerics (absmax 4.1e-2 = 10.5x bf16's 3.9e-3 — the e4m3 vs bf16
// mantissa ratio; scale factors can't fix precision-limited error). fp8 direction closed.
// Config: 32KB-LDS MFMA GEMMs (__launch_bounds__(256,4), two-pass epilogues), fused critic
// final q-dot, XCD chunk swizzle, R9 barriered f32-tile attn, bf16 intermediates throughout.
// A=8, B=8192, S=128, ADIM=16, H=512, HEADS=4, D=128. Output f32.

#define AN 8
#define BNB 8192
#define SN 128
#define ADN 16
#define HN 512
#define NHEADS 4
#define DN 128

typedef __hip_bfloat16 bf16;
typedef unsigned short u16;
typedef __attribute__((ext_vector_type(8))) short bf16x8;
typedef __attribute__((ext_vector_type(4))) float f32x4;

__device__ __forceinline__ float lrelu(float x){ return x > 0.f ? x : 0.01f*x; }
__device__ __forceinline__ float bflo(unsigned u){ return __uint_as_float(u << 16); }
__device__ __forceinline__ float bfhi(unsigned u){ return __uint_as_float(u & 0xffff0000u); }
__device__ __forceinline__ float bf2f(u16 u){ return __uint_as_float((unsigned)u << 16); }
__device__ __forceinline__ u16 f2bf(float v){
  union { bf16 h; u16 s; } cv; cv.h = __float2bfloat16(v); return cv.s;
}
__device__ __forceinline__ ushort4 f4bf(float4 v){
  ushort4 u; u.x=f2bf(v.x); u.y=f2bf(v.y); u.z=f2bf(v.z); u.w=f2bf(v.w); return u;
}

// async global->LDS, 16B per lane; LDS dest is wave-uniform base + lane*16
__device__ __forceinline__ void gload16(const u16* g, u16* l){
  __builtin_amdgcn_global_load_lds(
      (const __attribute__((address_space(1))) unsigned int*)(g),
      (__attribute__((address_space(3))) unsigned int*)(l), 16, 0, 0);
}

// ---------------- prep: bf16-pack sa rows [65536][192] + LN stats + action argmax ------------
__global__ __launch_bounds__(256) void prep_kernel(
    const float* __restrict__ states, const float* __restrict__ actions,
    u16* __restrict__ sa_bf, float2* __restrict__ st_s, float2* __restrict__ st_sa,
    int* __restrict__ aip)
{
  const int lane = threadIdx.x & 63;
  const int r = blockIdx.x*4 + (threadIdx.x >> 6);
  float2 sv = ((const float2*)(states + (size_t)r*SN))[lane];
  float s1 = sv.x + sv.y, q1 = sv.x*sv.x + sv.y*sv.y;
  float2 av = make_float2(0.f, 0.f);
  if (lane < 8) av = ((const float2*)(actions + (size_t)r*ADN))[lane];
  float s2 = s1 + av.x + av.y, q2 = q1 + av.x*av.x + av.y*av.y;
  #pragma unroll
  for (int off=32; off; off>>=1){
    s1 += __shfl_xor(s1,off); q1 += __shfl_xor(q1,off);
    s2 += __shfl_xor(s2,off); q2 += __shfl_xor(q2,off);
  }
  float bv; int bi;
  if (lane < 8){
    if (av.x >= av.y){ bv = av.x; bi = 2*lane; } else { bv = av.y; bi = 2*lane+1; }
  } else { bv = -INFINITY; bi = 999; }
  #pragma unroll
  for (int off=1; off<8; off<<=1){
    float ov = __shfl_xor(bv, off); int oi = __shfl_xor(bi, off);
    if (ov > bv || (ov == bv && oi < bi)){ bv = ov; bi = oi; }
  }
  u16* row = sa_bf + (size_t)r*192;
  ushort2 p; p.x = f2bf(sv.x); p.y = f2bf(sv.y);
  *(ushort2*)(row + 2*lane) = p;
  if (lane < 8){
    ushort2 pa; pa.x = f2bf(av.x); pa.y = f2bf(av.y);
    *(ushort2*)(row + 128 + 2*lane) = pa;
  } else if (lane < 32){
    ushort2 z; z.x = 0; z.y = 0;
    *(ushort2*)(row + 128 + 2*lane) = z;
  }
  if (lane==0){
    float m1 = s1*(1.f/128.f), v1 = fmaxf(q1*(1.f/128.f)-m1*m1, 0.f);
    st_s[r] = make_float2(m1, rsqrtf(v1+1e-5f));
    float m2 = s2*(1.f/144.f), v2 = fmaxf(q2*(1.f/144.f)-m2*m2, 0.f);
    st_sa[r] = make_float2(m2, rsqrtf(v2+1e-5f));
    aip[r] = bi;
  }
}

// ---------------- all weight transposes in one launch: [Z][K][N] f32 -> [Z][N][Kp] bf16 ------
__global__ __launch_bounds__(256) void transw_all_kernel(
    const float* __restrict__ Ws_s, const float* __restrict__ Ws_sa, const float* __restrict__ Wc1,
    const float* __restrict__ Wk, const float* __restrict__ Wv, const float* __restrict__ Wsel,
    u16* __restrict__ Wt_s, u16* __restrict__ Wt_sa, u16* __restrict__ Wt_c1, u16* __restrict__ Wt_p)
{
  __shared__ float t[32][33];
  int id = blockIdx.x;
  const float* in; u16* outp; int K, Kp; size_t zs; int gx;
  const int N = (id < 5376) ? 512 : 128;
  if (id < 512){            in=Ws_s;  outp=Wt_s;            K=128;  Kp=128;  zs=(size_t)512*128;  gx=4;  }
  else if (id < 1280){ id-=512;  in=Ws_sa; outp=Wt_sa;      K=144;  Kp=192;  zs=(size_t)512*192;  gx=6;  }
  else if (id < 5376){ id-=1280; in=Wc1;   outp=Wt_c1;      K=1024; Kp=1024; zs=(size_t)512*1024; gx=32; }
  else if (id < 5632){ id-=5376; in=Wk;    outp=Wt_p;            K=512; Kp=512; zs=(size_t)3*128*512; gx=16; }
  else if (id < 5888){ id-=5632; in=Wv;    outp=Wt_p+128*512;    K=512; Kp=512; zs=(size_t)3*128*512; gx=16; }
  else {               id-=5888; in=Wsel;  outp=Wt_p+2*128*512;  K=512; Kp=512; zs=(size_t)3*128*512; gx=16; }
  const int bx = id % gx; id /= gx;
  const int gy = N >> 5;
  const int by = id % gy;
  const int z  = id / gy;
  const int tx = threadIdx.x, ty = threadIdx.y;
  const int k0 = bx*32, n0 = by*32;
  const float* ip = in + (size_t)z*K*N;
  #pragma unroll
  for (int i=0;i<4;i++){
    int k = k0 + ty*4 + i;
    t[ty*4+i][tx] = (k < K) ? ip[(size_t)k*N + n0 + tx] : 0.f;
  }
  __syncthreads();
  u16* op = outp + (size_t)z*zs;
  #pragma unroll
  for (int i=0;i<4;i++){
    int n = n0 + ty*4 + i;
    op[(size_t)n*Kp + k0 + tx] = f2bf(t[tx][ty*4+i]);
  }
}

// ---------------- column sums from transposed bf16 weights (row-sums, 1 wave/row) ------------
__global__ __launch_bounds__(256) void colsum_bf_kernel(
    const u16* __restrict__ Wt_s, const u16* __restrict__ Wt_sa, const u16* __restrict__ Wt_c1,
    float* __restrict__ cs_s, float* __restrict__ cs_sa, float* __restrict__ cs_c1)
{
  const int lane = threadIdx.x & 63;
  const int row = blockIdx.x*4 + (threadIdx.x >> 6);
  const int which = row >> 12; const int idx = row & 4095;
  const u16* W; int K; float* outp;
  if (which==0){ W = Wt_s;  K = 128;  outp = cs_s;  }
  else if (which==1){ W = Wt_sa; K = 192;  outp = cs_sa; }
  else { W = Wt_c1; K = 1024; outp = cs_c1; }
  const u16* p = W + (size_t)idx*K;
  float s = 0.f;
  for (int c = lane*8; c < K; c += 512){
    uint4 v = *(const uint4*)(p + c);
    const unsigned w4[4] = {v.x, v.y, v.z, v.w};
    #pragma unroll
    for (int t=0;t<4;t++) s += bflo(w4[t]) + bfhi(w4[t]);
  }
  #pragma unroll
  for (int off=32; off; off>>=1) s += __shfl_xor(s,off);
  if (lane==0) outp[idx] = s;
}

// ---------------- MFMA GEMM + LN-fold epilogue (128x128 tile, encoders); 32KB LDS ------------
// MODE 0: s_enc = lrelu(ln(states)@Ws_s + bs_s)   K=128  A=sa_bf(lda 192)
// MODE 1: sa_enc= lrelu(ln([s|a])@Ws_sa + bs_sa)  K=192
template<int MODE>
__global__ __launch_bounds__(256, 4) void mfma_enc_kernel(
    const u16* __restrict__ Aa,
    const u16* __restrict__ Wt, const float* __restrict__ bias,
    const float2* __restrict__ stats, const float* __restrict__ csum,
    u16* __restrict__ outp)
{
  constexpr int K   = (MODE==0) ? 128 : 192;
  constexpr int LDA = 192;
  constexpr int KP  = K;
  __shared__ __align__(16) u16 smem[16384];   // As 16KB | Bs 16KB; epilogue reuses as [64][136]
  u16* As = smem;
  u16* Bs = smem + 8192;
  const int tid = threadIdx.x;
  const int w = tid>>6, lane = tid&63;
  const int wr = w>>1, wc = w&1;
  const int srow = lane>>3, skq = (lane&7)^srow;
  const int slotx = lane>>4, lr = lane&15;

  const int nwg = gridDim.x * gridDim.y;
  int id = blockIdx.y * gridDim.x + blockIdx.x;
  int swz = (id & 7) * (nwg >> 3) + (id >> 3);
  const int bx = swz % gridDim.x, by = swz / gridDim.x;

  const int m0 = by*128, n0c = bx*128;
  const int a = by >> 6;
  const u16* Wbase = Wt + (size_t)a*HN*KP;
  const int slotbase = slotx ^ (lane&7);
  f32x4 acc[4][4] = {};

  for (int k0 = 0; k0 < K; k0 += 64){
    __syncthreads();
    #pragma unroll
    for (int t=0;t<4;t++){
      const int rr = w*32 + t*8;
      gload16(Aa    + (size_t)(m0  + rr + srow)*LDA + k0 + skq*8, As + rr*64);
      gload16(Wbase + (size_t)(n0c + rr + srow)*KP  + k0 + skq*8, Bs + rr*64);
    }
    __syncthreads();
    #pragma unroll
    for (int ks=0; ks<2; ++ks){
      bf16x8 af[4], bv[4];
      const int so = ((slotbase ^ (ks<<2)))*8;
      #pragma unroll
      for (int mi=0;mi<4;mi++) af[mi] = *(const bf16x8*)&As[(wr*64+mi*16+lr)*64 + so];
      #pragma unroll
      for (int ni=0;ni<4;ni++) bv[ni] = *(const bf16x8*)&Bs[(wc*64+ni*16+lr)*64 + so];
      #pragma unroll
      for (int mi=0;mi<4;mi++)
        #pragma unroll
        for (int ni=0;ni<4;ni++)
          acc[mi][ni] = __builtin_amdgcn_mfma_f32_16x16x32_bf16(af[mi], bv[ni], acc[mi][ni], 0, 0, 0);
    }
  }

  __syncthreads();
  float csv[4], biv[4];
  #pragma unroll
  for (int ni=0;ni<4;ni++){
    const int col = n0c + wc*64 + ni*16 + lr;
    csv[ni] = csum[a*HN + col];
    biv[ni] = bias[a*HN + col];
  }
  // two-pass epilogue: pass p stages rows p*64..p*64+63 into smem[64][136]
  #pragma unroll
  for (int pass=0; pass<2; ++pass){
    if (wr == pass){
      #pragma unroll
      for (int mi=0;mi<4;mi++){
        const int rloc = mi*16 + slotx*4;
        #pragma unroll
        for (int v=0; v<4; ++v){
          const float2 st = stats[m0 + pass*64 + rloc + v];
          #pragma unroll
          for (int ni=0;ni<4;ni++){
            const float o = lrelu(st.y*(acc[mi][ni][v] - st.x*csv[ni]) + biv[ni]);
            smem[(rloc+v)*136 + wc*64 + ni*16 + lr] = f2bf(o);
          }
        }
      }
    }
    __syncthreads();
    #pragma unroll
    for (int it=0; it<4; ++it){
      const int rl = it*16 + (tid>>4);
      const int ck = (tid&15)*8;
      const uint4 vv = *(const uint4*)&smem[rl*136 + ck];
      *(uint4*)(outp + (size_t)(m0 + pass*64 + rl)*HN + n0c + ck) = vv;
    }
    __syncthreads();
  }
}

// ---------------- critic: 128x128 + fused final; 32KB LDS (wc2l loaded in epilogue) ----------
// q += (lrelu(ln([s_enc|values])@Wc1 + bc1)) . Wc2[:,argmax];  K=1024, atomicAdd f32.
__global__ __launch_bounds__(256, 4) void mfma_critic_kernel(
    const u16* __restrict__ Aa, const u16* __restrict__ Ab,
    const u16* __restrict__ Wt, const float* __restrict__ bias,
    const float2* __restrict__ stats, const float* __restrict__ csum,
    const float* __restrict__ Wc2, const float* __restrict__ bc2,
    const int* __restrict__ aip, float* __restrict__ qout)
{
  __shared__ __align__(16) u16 smem[16384];   // As|Bs during loop; wc2l[16][128]+ail after
  u16* As = smem;
  u16* Bs = smem + 8192;
  const int tid = threadIdx.x;
  const int w = tid>>6, lane = tid&63;
  const int wr = w>>1, wc = w&1;
  const int srow = lane>>3, skq = (lane&7)^srow;
  const int slotx = lane>>4, lr = lane&15;

  const int nwg = gridDim.x * gridDim.y;     // (4,512) = 2048, %8==0
  int id = blockIdx.y * gridDim.x + blockIdx.x;
  int swz = (id & 7) * (nwg >> 3) + (id >> 3);
  const int bx = swz % gridDim.x, by = swz / gridDim.x;

  const int m0 = by*128, n0c = bx*128;
  const int a = by >> 6;
  const u16* Wbase = Wt + (size_t)a*HN*1024;
  const int slotbase = slotx ^ (lane&7);
  f32x4 acc[4][4] = {};

  for (int k0 = 0; k0 < 1024; k0 += 64){
    __syncthreads();
    const u16* asrc = (k0 < 512) ? Aa : Ab;
    const int acol = k0 & 511;
    #pragma unroll
    for (int t=0;t<4;t++){
      const int rr = w*32 + t*8;
      gload16(asrc  + (size_t)(m0  + rr + srow)*HN   + acol + skq*8, As + rr*64);
      gload16(Wbase + (size_t)(n0c + rr + srow)*1024 + k0   + skq*8, Bs + rr*64);
    }
    __syncthreads();
    #pragma unroll
    for (int ks=0; ks<2; ++ks){
      bf16x8 af[4], bv[4];
      const int so = ((slotbase ^ (ks<<2)))*8;
      #pragma unroll
      for (int mi=0;mi<4;mi++) af[mi] = *(const bf16x8*)&As[(wr*64+mi*16+lr)*64 + so];
      #pragma unroll
      for (int ni=0;ni<4;ni++) bv[ni] = *(const bf16x8*)&Bs[(wc*64+ni*16+lr)*64 + so];
      #pragma unroll
      for (int mi=0;mi<4;mi++)
        #pragma unroll
        for (int ni=0;ni<4;ni++)
          acc[mi][ni] = __builtin_amdgcn_mfma_f32_16x16x32_bf16(af[mi], bv[ni], acc[mi][ni], 0, 0, 0);
    }
  }

  __syncthreads();
  // load Wc2 slice into freed As region: wc2l[aidx][col] bf16 (conflict-free epilogue reads)
  u16* wc2l = smem;                   // 2048 u16
  int* ail  = (int*)(smem + 2048);    // 128 int
  const float* wsrc = Wc2 + ((size_t)a*HN + n0c)*ADN;
  #pragma unroll
  for (int i = 0; i < 8; ++i){
    const int e = i*256 + tid;        // e = col*16 + aidx
    wc2l[(e & 15)*128 + (e >> 4)] = f2bf(wsrc[e]);
  }
  if (tid < 128) ail[tid] = aip[m0 + tid];
  __syncthreads();

  float csv[4], biv[4];
  #pragma unroll
  for (int ni=0;ni<4;ni++){
    const int col = n0c + wc*64 + ni*16 + lr;
    csv[ni] = csum[a*HN + col];
    biv[ni] = bias[a*HN + col];
  }
  #pragma unroll
  for (int mi=0;mi<4;mi++){
    const int rbase = wr*64 + mi*16 + slotx*4;
    #pragma unroll
    for (int v=0; v<4; ++v){
      const int rl = rbase + v;
      const float2 st = stats[m0 + rl];
      const int aidx = ail[rl];
      float p = 0.f;
      #pragma unroll
      for (int ni=0;ni<4;ni++){
        const int coll = wc*64 + ni*16 + lr;
        const float o = lrelu(st.y*(acc[mi][ni][v] - st.x*csv[ni]) + biv[ni]);
        p = fmaf(o, bf2f(wc2l[aidx*128 + coll]), p);
      }
      p += __shfl_xor(p,1); p += __shfl_xor(p,2);
      p += __shfl_xor(p,4); p += __shfl_xor(p,8);
      if (lr == 0){
        if (n0c==0 && wc==0) p += bc2[a*ADN + aidx];
        atomicAdd(qout + m0 + rl, p);
      }
    }
  }
}

// ---------------- MFMA proj (one head): N=128 per t-block, K=512; 32KB LDS -------------------
__global__ __launch_bounds__(256, 4) void mfma_proj_kernel(
    const u16* __restrict__ sa_enc, const u16* __restrict__ Wt_p,
    const float* __restrict__ bsel, u16* __restrict__ kvs, int head)
{
  __shared__ __align__(16) u16 smem[16384];
  u16* As = smem;
  u16* Bs = smem + 8192;
  const int tid = threadIdx.x;
  const int w = tid>>6, lane = tid&63;
  const int wr = w>>1, wc = w&1;
  const int srow = lane>>3, skq = (lane&7)^srow;
  const int slotx = lane>>4, lr = lane&15;

  const int nwg = gridDim.x * gridDim.y;              // (3, 512) = 1536, %8==0
  int id = blockIdx.y * gridDim.x + blockIdx.x;
  int swz = (id & 7) * (nwg >> 3) + (id >> 3);
  const int t = swz % gridDim.x;
  const int m0 = (swz / gridDim.x) * 128;

  const u16* Wbase = Wt_p + (size_t)(head*3 + t)*DN*HN;
  const int slotbase = slotx ^ (lane&7);
  f32x4 acc[4][4] = {};

  for (int k0 = 0; k0 < HN; k0 += 64){
    __syncthreads();
    #pragma unroll
    for (int tt=0;tt<4;tt++){
      const int rr = w*32 + tt*8;
      gload16(sa_enc + (size_t)(m0 + rr + srow)*HN + k0 + skq*8, As + rr*64);
      gload16(Wbase  + (size_t)(rr + srow)*HN      + k0 + skq*8, Bs + rr*64);
    }
    __syncthreads();
    #pragma unroll
    for (int ks=0; ks<2; ++ks){
      bf16x8 af[4], bv[4];
      const int so = ((slotbase ^ (ks<<2)))*8;
      #pragma unroll
      for (int mi=0;mi<4;mi++) af[mi] = *(const bf16x8*)&As[(wr*64+mi*16+lr)*64 + so];
      #pragma unroll
      for (int ni=0;ni<4;ni++) bv[ni] = *(const bf16x8*)&Bs[(wc*64+ni*16+lr)*64 + so];
      #pragma unroll
      for (int mi=0;mi<4;mi++)
        #pragma unroll
        for (int ni=0;ni<4;ni++)
          acc[mi][ni] = __builtin_amdgcn_mfma_f32_16x16x32_bf16(af[mi], bv[ni], acc[mi][ni], 0, 0, 0);
    }
  }

  __syncthreads();
  const bool issel = (t == 2);
  float biv[4];
  #pragma unroll
  for (int ni=0;ni<4;ni++){
    const int col = wc*64 + ni*16 + lr;
    biv[ni] = issel ? bsel[head*DN + col] : 0.f;
  }
  // two-pass epilogue staging into smem[64][136]
  #pragma unroll
  for (int pass=0; pass<2; ++pass){
    if (wr == pass){
      #pragma unroll
      for (int mi=0;mi<4;mi++){
        const int rloc = mi*16 + slotx*4;
        #pragma unroll
        for (int v=0; v<4; ++v){
          #pragma unroll
          for (int ni=0;ni<4;ni++){
            float o = acc[mi][ni][v] + biv[ni];
            if (issel) o = lrelu(o);
            smem[(rloc+v)*136 + wc*64 + ni*16 + lr] = f2bf(o);
          }
        }
      }
    }
    __syncthreads();
    #pragma unroll
    for (int it=0; it<4; ++it){
      const int rl = it*16 + (tid>>4);
      const int ck = (tid&15)*8;
      const int r = m0 + pass*64 + rl;
      const int ar = r >> 13, b = r & (BNB-1);
      const uint4 vv = *(const uint4*)&smem[rl*136 + ck];
      *(uint4*)(kvs + (((size_t)t*BNB + b)*AN + ar)*DN + ck) = vv;
    }
    __syncthreads();
  }
}

// ---------------- attention for ONE head: one wave per b (R9 f32-tile version) ---------------
__global__ __launch_bounds__(256) void attn_kernel(
    const u16* __restrict__ kvs, u16* __restrict__ values, int kh)
{
  __shared__ float lds[4][3232];
  const int lane = threadIdx.x & 63;
  const int wv   = threadIdx.x >> 6;
  float* selL = &lds[wv][0];
  float* keyL = &lds[wv][1056];
  float* valL = &lds[wv][2112];
  float* wL   = &lds[wv][3168];
  const int b = blockIdx.x*4 + wv;

  #pragma unroll
  for (int m=0;m<3;m++){
    const int t = (m==0) ? 2 : ((m==1) ? 0 : 1);
    float* dst = (m==0) ? selL : ((m==1) ? keyL : valL);
    const uint2* p = (const uint2*)(kvs + ((size_t)t*BNB + b)*(AN*DN));
    #pragma unroll
    for (int it=0; it<4; it++){
      uint2 u = p[it*64 + lane];
      int e = (it*64 + lane)*4;
      int j = e >> 7, d = e & 127;
      float4 f;
      f.x = bflo(u.x); f.y = bfhi(u.x); f.z = bflo(u.y); f.w = bfhi(u.y);
      *(float4*)&dst[j*132 + d] = f;
    }
  }
  __syncthreads();

  const int i = lane >> 3, j = lane & 7;
  float acc = 0.f;
  #pragma unroll 8
  for (int dq=0; dq<32; dq++){
    const float4 s4 = *(const float4*)&selL[i*132 + dq*4];
    const float4 k4 = *(const float4*)&keyL[j*132 + dq*4];
    acc += s4.x*k4.x + s4.y*k4.y + s4.z*k4.z + s4.w*k4.w;
  }
  float logit = acc * 0.08838834764831845f;
  if (i == j) logit = -INFINITY;
  float mx = logit;
  mx = fmaxf(mx, __shfl_xor(mx,1,8));
  mx = fmaxf(mx, __shfl_xor(mx,2,8));
  mx = fmaxf(mx, __shfl_xor(mx,4,8));
  const float e = __expf(logit - mx);
  float s = e;
  s += __shfl_xor(s,1,8);
  s += __shfl_xor(s,2,8);
  s += __shfl_xor(s,4,8);
  wL[i*8 + j] = e / s;
  __syncthreads();

  const int dq = lane & 7;
  float4 o[4];
  #pragma unroll
  for (int tt=0;tt<4;tt++) o[tt] = make_float4(0.f,0.f,0.f,0.f);
  #pragma unroll
  for (int jj=0;jj<8;jj++){
    const float wj = wL[i*8 + jj];
    #pragma unroll
    for (int tt=0;tt<4;tt++){
      const float4 v4 = *(const float4*)&valL[jj*132 + tt*32 + dq*4];
      o[tt].x += wj*v4.x; o[tt].y += wj*v4.y; o[tt].z += wj*v4.z; o[tt].w += wj*v4.w;
    }
  }
  u16* dst = values + ((size_t)i*BNB + b)*HN + kh*DN;
  #pragma unroll
  for (int tt=0;tt<4;tt++)
    *(ushort4*)(dst + tt*32 + dq*4) = f4bf(o[tt]);
}

// ---------------- per-row stats of cin = concat(s_enc, values) (1024), bf16 inputs -----------
__global__ __launch_bounds__(256) void stats_cin_kernel(
    const u16* __restrict__ s_enc, const u16* __restrict__ values, float2* __restrict__ st)
{
  const int lane = threadIdx.x & 63;
  const int r = blockIdx.x*4 + (threadIdx.x >> 6);
  const uint4* p1 = (const uint4*)(s_enc + (size_t)r*HN);
  const uint4* p2 = (const uint4*)(values + (size_t)r*HN);
  uint4 va = p1[lane];
  uint4 vb = p2[lane];
  float s=0.f, q=0.f;
  const unsigned wa[4] = {va.x, va.y, va.z, va.w};
  const unsigned wb[4] = {vb.x, vb.y, vb.z, vb.w};
  #pragma unroll
  for (int t=0;t<4;t++){
    float f0 = bflo(wa[t]), f1 = bfhi(wa[t]);
    float g0 = bflo(wb[t]), g1 = bfhi(wb[t]);
    s += f0+f1+g0+g1; q += f0*f0+f1*f1+g0*g0+g1*g1;
  }
  #pragma unroll
  for (int off=32; off; off>>=1){ s += __shfl_xor(s,off); q += __shfl_xor(q,off); }
  if (lane==0){
    float m = s*(1.f/1024.f); float v = fmaxf(q*(1.f/1024.f) - m*m, 0.f);
    st[r] = make_float2(m, rsqrtf(v + 1e-5f));
  }
}

extern "C" void kernel_launch(void* const* d_in, const int* in_sizes, int n_in,
                              void* d_out, int out_size, void* d_ws, size_t ws_size,
                              hipStream_t stream)
{
  (void)in_sizes; (void)n_in; (void)ws_size;
  const float* states  = (const float*)d_in[0];
  const float* actions = (const float*)d_in[1];
  const float* Ws_s    = (const float*)d_in[2];
  const float* bs_s    = (const float*)d_in[3];
  const float* Ws_sa   = (const float*)d_in[4];
  const float* bs_sa   = (const float*)d_in[5];
  const float* Wk      = (const float*)d_in[6];
  const float* Wv      = (const float*)d_in[7];
  const float* Wsel    = (const float*)d_in[8];
  const float* bsel    = (const float*)d_in[9];
  const float* Wc1     = (const float*)d_in[10];
  const float* bc1     = (const float*)d_in[11];
  const float* Wc2     = (const float*)d_in[12];
  const float* bc2     = (const float*)d_in[13];
  float* outp = (float*)d_out;

  char* ws = (char*)d_ws;
  size_t off = 0;
  auto alloc = [&](size_t n){ void* p = ws + off; off += (n + 255) & ~(size_t)255; return p; };
  u16*    slot1  = (u16*)   alloc((size_t)AN*BNB*HN*2);   // 64 MB: kvs during attn loop, s_enc after
  u16*    s_enc  = slot1;
  u16*    kvs    = slot1;                                  // 48 MB <= 64 MB
  u16*    sa_enc = (u16*)   alloc((size_t)AN*BNB*HN*2);   // 64 MB
  u16*    values = (u16*)   alloc((size_t)AN*BNB*HN*2);   // 64 MB
  u16*    sa_bf  = (u16*)   alloc((size_t)AN*BNB*192*2);  // 24 MB
  u16*    Wt_s   = (u16*)   alloc((size_t)AN*HN*128*2);
  u16*    Wt_sa  = (u16*)   alloc((size_t)AN*HN*192*2);
  u16*    Wt_c1  = (u16*)   alloc((size_t)AN*HN*1024*2);
  u16*    Wt_p   = (u16*)   alloc((size_t)NHEADS*3*DN*HN*2);
  float2* st_s   = (float2*)alloc((size_t)AN*BNB*8);
  float2* st_sa  = (float2*)alloc((size_t)AN*BNB*8);
  float2* st_cin = (float2*)alloc((size_t)AN*BNB*8);
  float*  cs_s   = (float*) alloc((size_t)AN*HN*4);
  float*  cs_sa  = (float*) alloc((size_t)AN*HN*4);
  float*  cs_c1  = (float*) alloc((size_t)AN*HN*4);
  int*    aip    = (int*)   alloc((size_t)AN*BNB*4);

  hipMemsetAsync(d_out, 0, (size_t)out_size*4, stream);
  prep_kernel<<<dim3(AN*BNB/4), 256, 0, stream>>>(states, actions, sa_bf, st_s, st_sa, aip);
  transw_all_kernel<<<dim3(6144), dim3(32,8), 0, stream>>>(
      Ws_s, Ws_sa, Wc1, Wk, Wv, Wsel, Wt_s, Wt_sa, Wt_c1, Wt_p);
  colsum_bf_kernel<<<dim3(3*AN*HN/4), 256, 0, stream>>>(Wt_s, Wt_sa, Wt_c1, cs_s, cs_sa, cs_c1);

  mfma_enc_kernel<1><<<dim3(4,512), 256, 0, stream>>>(sa_bf, Wt_sa, bs_sa, st_sa, cs_sa, sa_enc);
  for (int kh = 0; kh < NHEADS; ++kh){
    mfma_proj_kernel<<<dim3(3,512), 256, 0, stream>>>(sa_enc, Wt_p, bsel, kvs, kh);
    attn_kernel<<<dim3(BNB/4), 256, 0, stream>>>(kvs, values, kh);
  }
  mfma_enc_kernel<0><<<dim3(4,512), 256, 0, stream>>>(sa_bf, Wt_s, bs_s, st_s, cs_s, s_enc);
  stats_cin_kernel<<<dim3(AN*BNB/4), 256, 0, stream>>>(s_enc, values, st_cin);
  mfma_critic_kernel<<<dim3(4,512), 256, 0, stream>>>(s_enc, values, Wt_c1, bc1, st_cin, cs_c1,
                                                      Wc2, bc2, aip, outp);
}